// Round 2
// baseline (708.303 us; speedup 1.0000x reference)
//
#include <hip/hip_runtime.h>
#include <hip/hip_bf16.h>

typedef unsigned short u16;
typedef u16 u16x4 __attribute__((ext_vector_type(4)));
typedef __bf16 bf16x8 __attribute__((ext_vector_type(8)));
typedef float f32x4 __attribute__((ext_vector_type(4)));

#define IN_DIM 4096
#define OUT_DIM 4096
#define M_TOT 8192   // 4 * 2048

__device__ __constant__ float NF4_LUT[16] = {
    -1.0f, -0.6961928009986877f, -0.5250730514526367f, -0.39491748809814453f,
    -0.28444138169288635f, -0.18477343022823334f, -0.09105003625154495f, 0.0f,
    0.07958029955625534f, 0.16093020141124725f, 0.24611230194568634f,
    0.33791524171829224f, 0.44070982933044434f, 0.5626170039176941f,
    0.7229568362236023f, 1.0f};

__device__ __forceinline__ u16 f2bf(float f) {  // round-to-nearest-even
  unsigned i = __float_as_uint(f);
  i += 0x7fffu + ((i >> 16) & 1u);
  return (u16)(i >> 16);
}

// ---------------------------------------------------------------------------
// Kernel 0: cast x fp32 -> bf16 into workspace.
// ---------------------------------------------------------------------------
__global__ __launch_bounds__(256) void convert_x(
    const float4* __restrict__ xin, u16x4* __restrict__ xout, int n4)
{
  int i = blockIdx.x * 256 + threadIdx.x;
  const int stride = gridDim.x * 256;
  for (; i < n4; i += stride) {
    const float4 v = xin[i];
    u16x4 o;
    o.x = f2bf(v.x); o.y = f2bf(v.y); o.z = f2bf(v.z); o.w = f2bf(v.w);
    xout[i] = o;
  }
}

// ---------------------------------------------------------------------------
// Kernel 1: dequantize NF4 -> fp32, fold LoRA (W_eff = W + 2*B*A), store bf16.
// One block per output row o. 256 threads, 4 elements/thread/iter, 4 iters.
// ---------------------------------------------------------------------------
__global__ __launch_bounds__(256) void dequant_fold(
    const int* __restrict__ nf4_idx, const int* __restrict__ q_scalers,
    const float* __restrict__ q_factor, const float* __restrict__ scaler_mean,
    const float* __restrict__ lora_a, const float* __restrict__ lora_b,
    u16* __restrict__ w_eff)
{
  __shared__ float s_lut[16];
  __shared__ float s_b[16];
  __shared__ float s_scl[64];
  const int t = threadIdx.x;
  const int o = blockIdx.x;
  if (t < 16) {
    s_lut[t] = NF4_LUT[t];
    s_b[t] = 2.0f * lora_b[o * 16 + t];   // ALPHA/RANK = 2 folded here
  }
  if (t < 64) {
    const int b = o * 64 + t;             // nf4-block index within this row
    s_scl[t] = (float)q_scalers[b] / q_factor[b >> 8] + scaler_mean[0];
  }
  __syncthreads();

  float Bf[16];
#pragma unroll
  for (int r = 0; r < 16; ++r) Bf[r] = s_b[r];

#pragma unroll
  for (int it = 0; it < 4; ++it) {
    const int d0 = it * 1024 + t * 4;
    const int4 iv = *(const int4*)(nf4_idx + (size_t)o * IN_DIM + d0);
    const float sc = s_scl[d0 >> 6];
    float l0 = 0.f, l1 = 0.f, l2 = 0.f, l3 = 0.f;
#pragma unroll
    for (int r = 0; r < 16; ++r) {
      const float4 av = *(const float4*)(lora_a + (size_t)r * IN_DIM + d0);
      const float br = Bf[r];
      l0 += br * av.x;
      l1 += br * av.y;
      l2 += br * av.z;
      l3 += br * av.w;
    }
    u16x4 ov;
    ov.x = f2bf(s_lut[iv.x] * sc + l0);
    ov.y = f2bf(s_lut[iv.y] * sc + l1);
    ov.z = f2bf(s_lut[iv.z] * sc + l2);
    ov.w = f2bf(s_lut[iv.w] * sc + l3);
    *(u16x4*)(w_eff + (size_t)o * IN_DIM + d0) = ov;
  }
}

// ---------------------------------------------------------------------------
// Kernel 2: bf16 GEMM, m97 structure, fp32 output.
// C[M, N] = X[M, K] * W[N, K]^T.  128x128 tile, BK=32, 4 waves (2x2),
// each wave: 4x4 tiles of mfma_f32_16x16x32_bf16.
// Staging: global_load_lds width=16, lane-contiguous LDS layout (no padding).
// ---------------------------------------------------------------------------
__device__ __forceinline__ void async16(const u16* g, u16* l) {
  __builtin_amdgcn_global_load_lds(
      (const __attribute__((address_space(1))) void*)g,
      (__attribute__((address_space(3))) void*)l,
      16, 0, 0);
}

__global__ __launch_bounds__(256) void gemm_bt(
    const u16* __restrict__ X, const u16* __restrict__ W,
    float* __restrict__ Out)
{
  __shared__ __align__(16) u16 sA[128 * 32];
  __shared__ __align__(16) u16 sB[128 * 32];
  const int tid = threadIdx.x;
  const int lane = tid & 63;
  const int wid = tid >> 6;
  const int wm = wid >> 1, wn = wid & 1;
  const int row0 = blockIdx.y * 128;
  const int col0 = blockIdx.x * 128;

  // Staging: 8 KB per tile = 512 16B-chunks; thread stages chunks tid, tid+256.
  // chunk c -> tile row m = c>>2, k-offset (c&3)*8 elements.
  const int m0 = tid >> 2, q0 = (tid & 3) * 8;
  const int m1 = (tid + 256) >> 2, q1 = ((tid + 256) & 3) * 8;
  const u16* gA0 = X + (size_t)(row0 + m0) * IN_DIM + q0;
  const u16* gA1 = X + (size_t)(row0 + m1) * IN_DIM + q1;
  const u16* gB0 = W + (size_t)(col0 + m0) * IN_DIM + q0;
  const u16* gB1 = W + (size_t)(col0 + m1) * IN_DIM + q1;
  // wave-uniform LDS bases (lane-contiguous destinations, HW adds lane*16B)
  u16* lA0 = sA + wid * 512;
  u16* lA1 = sA + 2048 + wid * 512;
  u16* lB0 = sB + wid * 512;
  u16* lB1 = sB + 2048 + wid * 512;

  const int rA = lane & 15;            // fragment row (A) / col (B)
  const int qk = (lane >> 4) * 8;      // fragment k-offset

  f32x4 acc[4][4] = {};

  for (int kt = 0; kt < IN_DIM; kt += 32) {
    async16(gA0 + kt, lA0);
    async16(gA1 + kt, lA1);
    async16(gB0 + kt, lB0);
    async16(gB1 + kt, lB1);
    __syncthreads();   // drains vmcnt (global_load_lds) before fragment reads

    bf16x8 af[4], bfr[4];
#pragma unroll
    for (int i = 0; i < 4; ++i)
      af[i] = *(const bf16x8*)&sA[(wm * 64 + i * 16 + rA) * 32 + qk];
#pragma unroll
    for (int i = 0; i < 4; ++i)
      bfr[i] = *(const bf16x8*)&sB[(wn * 64 + i * 16 + rA) * 32 + qk];
#pragma unroll
    for (int mi = 0; mi < 4; ++mi)
#pragma unroll
      for (int ni = 0; ni < 4; ++ni)
        acc[mi][ni] = __builtin_amdgcn_mfma_f32_16x16x32_bf16(
            af[mi], bfr[ni], acc[mi][ni], 0, 0, 0);
    __syncthreads();   // LDS reads done before next iteration overwrites
  }

  // Epilogue: C/D layout col=lane&15, row=(lane>>4)*4+reg.  fp32 stores.
  const int or4 = (lane >> 4) * 4;
#pragma unroll
  for (int mi = 0; mi < 4; ++mi) {
#pragma unroll
    for (int i = 0; i < 4; ++i) {
      const size_t r = (size_t)(row0 + wm * 64 + mi * 16 + or4 + i);
      float* po = Out + r * OUT_DIM + col0 + wn * 64 + rA;
#pragma unroll
      for (int ni = 0; ni < 4; ++ni)
        po[ni * 16] = acc[mi][ni][i];
    }
  }
}

extern "C" void kernel_launch(void* const* d_in, const int* in_sizes, int n_in,
                              void* d_out, int out_size, void* d_ws, size_t ws_size,
                              hipStream_t stream) {
  const float* x         = (const float*)d_in[0];
  const int* nf4_idx     = (const int*)d_in[1];
  const int* q_scalers   = (const int*)d_in[2];
  const float* q_factor  = (const float*)d_in[3];
  const float* scaler_mean = (const float*)d_in[4];
  const float* lora_a    = (const float*)d_in[5];
  const float* lora_b    = (const float*)d_in[6];
  float* out = (float*)d_out;

  // ws layout: [0, 64MB) x as bf16; [64MB, 96MB) W_eff as bf16.
  const size_t xbf_bytes = (size_t)M_TOT * IN_DIM * sizeof(u16);
  const size_t wef_bytes = (size_t)OUT_DIM * IN_DIM * sizeof(u16);
  if (ws_size < xbf_bytes + wef_bytes) return;  // need 96 MB
  u16* xbf   = (u16*)d_ws;
  u16* w_eff = (u16*)((char*)d_ws + xbf_bytes);

  hipLaunchKernelGGL(convert_x, dim3(8192), dim3(256), 0, stream,
                     (const float4*)x, (u16x4*)xbf, M_TOT * IN_DIM / 4);
  hipLaunchKernelGGL(dequant_fold, dim3(OUT_DIM), dim3(256), 0, stream,
                     nf4_idx, q_scalers, q_factor, scaler_mean, lora_a, lora_b,
                     w_eff);
  hipLaunchKernelGGL(gemm_bt, dim3(OUT_DIM / 128, M_TOT / 128), dim3(256), 0,
                     stream, xbf, w_eff, out);
}